// Round 2
// baseline (249.294 us; speedup 1.0000x reference)
//
#include <hip/hip_runtime.h>
#include <math.h>

#define B_ROWS 4096
#define D_DIM  2048
#define MARGIN_F 0.05f
#define HUBER_DELTA_F 0.1f
#define COS_EPS_F 1e-8f

// Kernel A: one block per row. Computes cosine sim, stages overall[], and
// accumulates the Huber sum (4 elems/row) into acc[1].
__global__ __launch_bounds__(256) void sim_huber_kernel(
    const float* __restrict__ z_ref, const float* __restrict__ z_perf,
    const float* __restrict__ pred, const float* __restrict__ tgt,
    float* __restrict__ sim, float* __restrict__ overall, float* __restrict__ acc)
{
    const int row = blockIdx.x;
    const int tid = threadIdx.x;
    const float4* a4 = (const float4*)(z_ref + (size_t)row * D_DIM);
    const float4* b4 = (const float4*)(z_perf + (size_t)row * D_DIM);

    float dot = 0.f, na2 = 0.f, nb2 = 0.f;
    #pragma unroll
    for (int k = 0; k < 2; ++k) {
        const int idx = tid + k * 256;        // 512 float4 per row
        float4 a = a4[idx];
        float4 b = b4[idx];
        dot += a.x*b.x + a.y*b.y + a.z*b.z + a.w*b.w;
        na2 += a.x*a.x + a.y*a.y + a.z*a.z + a.w*a.w;
        nb2 += b.x*b.x + b.y*b.y + b.z*b.z + b.w*b.w;
    }

    // Huber partials for this row's 4 score elements
    __shared__ float hs[4];
    if (tid < 4) {
        float d  = pred[row * 4 + tid] - tgt[row * 5 + tid];
        float ad = fabsf(d);
        hs[tid] = (ad <= HUBER_DELTA_F) ? 0.5f * d * d
                                        : HUBER_DELTA_F * (ad - 0.5f * HUBER_DELTA_F);
    }

    const int lane = tid & 63, wave = tid >> 6;
    #pragma unroll
    for (int off = 32; off > 0; off >>= 1) {
        dot += __shfl_down(dot, off, 64);
        na2 += __shfl_down(na2, off, 64);
        nb2 += __shfl_down(nb2, off, 64);
    }
    __shared__ float shm[3][4];
    if (lane == 0) { shm[0][wave] = dot; shm[1][wave] = na2; shm[2][wave] = nb2; }
    __syncthreads();
    if (tid == 0) {
        float dt = shm[0][0] + shm[0][1] + shm[0][2] + shm[0][3];
        float na = sqrtf(shm[1][0] + shm[1][1] + shm[1][2] + shm[1][3]);
        float nb = sqrtf(shm[2][0] + shm[2][1] + shm[2][2] + shm[2][3]);
        na = fmaxf(na, COS_EPS_F);
        nb = fmaxf(nb, COS_EPS_F);
        sim[row] = dt / (na * nb);
        overall[row] = tgt[row * 5 + 4];
        atomicAdd(&acc[1], hs[0] + hs[1] + hs[2] + hs[3]);
    }
}

// Kernel B: block i handles pair-row i. mask[i][j] = overall[i] > overall[j];
// pair_loss[i][j] = relu(sim[j] - sim[i] + MARGIN). sim/overall (32 KiB total)
// stay hot in cache across all 4096 blocks.
__global__ __launch_bounds__(256) void pair_kernel(
    const float* __restrict__ sim, const float* __restrict__ overall,
    float* __restrict__ acc, unsigned int* __restrict__ cnt_acc)
{
    const int i = blockIdx.x;
    const int tid = threadIdx.x;
    const float s_i = sim[i];
    const float o_i = overall[i];

    float part = 0.f;
    unsigned int cnt = 0;
    for (int j = tid; j < B_ROWS; j += 256) {
        float o_j = overall[j];
        if (o_i > o_j) {
            float d = sim[j] - s_i + MARGIN_F;
            part += fmaxf(d, 0.f);
            cnt++;
        }
    }

    const int lane = tid & 63, wave = tid >> 6;
    #pragma unroll
    for (int off = 32; off > 0; off >>= 1) {
        part += __shfl_down(part, off, 64);
        cnt  += __shfl_down(cnt,  off, 64);
    }
    __shared__ float pw[4];
    __shared__ unsigned int cw[4];
    if (lane == 0) { pw[wave] = part; cw[wave] = cnt; }
    __syncthreads();
    if (tid == 0) {
        atomicAdd(&acc[0], pw[0] + pw[1] + pw[2] + pw[3]);
        atomicAdd(cnt_acc, cw[0] + cw[1] + cw[2] + cw[3]);
    }
}

__global__ void finalize_kernel(const float* __restrict__ acc,
                                const unsigned int* __restrict__ cnt,
                                float* __restrict__ out)
{
    float n   = (float)(*cnt);
    float L_c = (n > 0.f) ? acc[0] / fmaxf(n, 1.f) : 0.f;
    float L_s = acc[1] / (float)(B_ROWS * 4);
    out[0] = L_c + L_s;
    out[1] = L_c;
    out[2] = L_s;
}

extern "C" void kernel_launch(void* const* d_in, const int* in_sizes, int n_in,
                              void* d_out, int out_size, void* d_ws, size_t ws_size,
                              hipStream_t stream) {
    const float* z_ref  = (const float*)d_in[0];
    const float* z_perf = (const float*)d_in[1];
    const float* pred   = (const float*)d_in[2];
    const float* tgt    = (const float*)d_in[3];
    float* out = (float*)d_out;

    // Workspace layout (floats): [0,4096)=sim, [4096,8192)=overall,
    // [8192]=pair_total, [8193]=huber_sum, [8194]=pair_count (uint bits)
    float* ws      = (float*)d_ws;
    float* sim     = ws;
    float* overall = ws + B_ROWS;
    float* acc     = ws + 2 * B_ROWS;
    unsigned int* cnt = (unsigned int*)(ws + 2 * B_ROWS + 2);

    hipMemsetAsync(acc, 0, 3 * sizeof(float), stream);  // zero acc[0..1] + cnt

    sim_huber_kernel<<<B_ROWS, 256, 0, stream>>>(z_ref, z_perf, pred, tgt, sim, overall, acc);
    pair_kernel<<<B_ROWS, 256, 0, stream>>>(sim, overall, acc, cnt);
    finalize_kernel<<<1, 1, 0, stream>>>(acc, cnt, out);
}

// Round 3
// 106.890 us; speedup vs baseline: 2.3322x; 2.3322x over previous
//
#include <hip/hip_runtime.h>
#include <math.h>

#define B_ROWS 4096
#define D_DIM  2048
#define PAIR_BLOCKS 1024
#define ROWS_PER_PAIR_BLOCK (B_ROWS / PAIR_BLOCKS)   // 4
#define MARGIN_F 0.05f
#define HUBER_DELTA_F 0.1f
#define COS_EPS_F 1e-8f

// Kernel A: one block per row. Computes cosine sim + overall[], and writes the
// row's Huber partial to hub_part[row]. NO atomics (R2: 4096 same-address
// atomicAdds serialized at L2 ≈ 100 µs — the round-2 bottleneck).
__global__ __launch_bounds__(256) void sim_huber_kernel(
    const float* __restrict__ z_ref, const float* __restrict__ z_perf,
    const float* __restrict__ pred, const float* __restrict__ tgt,
    float* __restrict__ sim, float* __restrict__ overall,
    float* __restrict__ hub_part)
{
    const int row = blockIdx.x;
    const int tid = threadIdx.x;
    const float4* a4 = (const float4*)(z_ref + (size_t)row * D_DIM);
    const float4* b4 = (const float4*)(z_perf + (size_t)row * D_DIM);

    float dot = 0.f, na2 = 0.f, nb2 = 0.f;
    #pragma unroll
    for (int k = 0; k < 2; ++k) {
        const int idx = tid + k * 256;        // 512 float4 per row
        float4 a = a4[idx];
        float4 b = b4[idx];
        dot += a.x*b.x + a.y*b.y + a.z*b.z + a.w*b.w;
        na2 += a.x*a.x + a.y*a.y + a.z*a.z + a.w*a.w;
        nb2 += b.x*b.x + b.y*b.y + b.z*b.z + b.w*b.w;
    }

    // Huber partials for this row's 4 score elements
    __shared__ float hs[4];
    if (tid < 4) {
        float d  = pred[row * 4 + tid] - tgt[row * 5 + tid];
        float ad = fabsf(d);
        hs[tid] = (ad <= HUBER_DELTA_F) ? 0.5f * d * d
                                        : HUBER_DELTA_F * (ad - 0.5f * HUBER_DELTA_F);
    }

    const int lane = tid & 63, wave = tid >> 6;
    #pragma unroll
    for (int off = 32; off > 0; off >>= 1) {
        dot += __shfl_down(dot, off, 64);
        na2 += __shfl_down(na2, off, 64);
        nb2 += __shfl_down(nb2, off, 64);
    }
    __shared__ float shm[3][4];
    if (lane == 0) { shm[0][wave] = dot; shm[1][wave] = na2; shm[2][wave] = nb2; }
    __syncthreads();
    if (tid == 0) {
        float dt = shm[0][0] + shm[0][1] + shm[0][2] + shm[0][3];
        float na = sqrtf(shm[1][0] + shm[1][1] + shm[1][2] + shm[1][3]);
        float nb = sqrtf(shm[2][0] + shm[2][1] + shm[2][2] + shm[2][3]);
        na = fmaxf(na, COS_EPS_F);
        nb = fmaxf(nb, COS_EPS_F);
        sim[row] = dt / (na * nb);
        overall[row] = tgt[row * 5 + 4];
        hub_part[row] = hs[0] + hs[1] + hs[2] + hs[3];
    }
}

// Kernel B: 1024 blocks; block b handles i-rows [4b, 4b+4). sim/overall staged
// in LDS once per block (kills the per-iteration L2-latency loads), each LDS
// j-read reused across 4 i-rows. Partials go to unique slots — no atomics.
__global__ __launch_bounds__(256) void pair_kernel(
    const float* __restrict__ sim, const float* __restrict__ overall,
    float* __restrict__ pair_part, unsigned int* __restrict__ cnt_part)
{
    __shared__ float ls[B_ROWS];
    __shared__ float lo[B_ROWS];
    const int tid = threadIdx.x;

    const float4* s4 = (const float4*)sim;
    const float4* o4 = (const float4*)overall;
    float4* ls4 = (float4*)ls;
    float4* lo4 = (float4*)lo;
    #pragma unroll
    for (int k = 0; k < (B_ROWS / 4) / 256; ++k) {   // 4 iters
        const int idx = tid + k * 256;
        ls4[idx] = s4[idx];
        lo4[idx] = o4[idx];
    }
    __syncthreads();

    const int i0 = blockIdx.x * ROWS_PER_PAIR_BLOCK;
    float s_i[ROWS_PER_PAIR_BLOCK], o_i[ROWS_PER_PAIR_BLOCK];
    #pragma unroll
    for (int ii = 0; ii < ROWS_PER_PAIR_BLOCK; ++ii) {
        s_i[ii] = ls[i0 + ii];
        o_i[ii] = lo[i0 + ii];
    }

    float part = 0.f;
    unsigned int cnt = 0;
    for (int j = tid; j < B_ROWS; j += 256) {        // 16 iters
        float sj = ls[j];
        float oj = lo[j];
        #pragma unroll
        for (int ii = 0; ii < ROWS_PER_PAIR_BLOCK; ++ii) {
            if (o_i[ii] > oj) {
                part += fmaxf(sj - s_i[ii] + MARGIN_F, 0.f);
                cnt++;
            }
        }
    }

    const int lane = tid & 63, wave = tid >> 6;
    #pragma unroll
    for (int off = 32; off > 0; off >>= 1) {
        part += __shfl_down(part, off, 64);
        cnt  += __shfl_down(cnt,  off, 64);
    }
    __shared__ float pw[4];
    __shared__ unsigned int cw[4];
    if (lane == 0) { pw[wave] = part; cw[wave] = cnt; }
    __syncthreads();
    if (tid == 0) {
        pair_part[blockIdx.x] = pw[0] + pw[1] + pw[2] + pw[3];
        cnt_part[blockIdx.x]  = cw[0] + cw[1] + cw[2] + cw[3];
    }
}

// Kernel C: single block reduces all partials and writes the 3 outputs.
__global__ __launch_bounds__(256) void finalize_kernel(
    const float* __restrict__ hub_part, const float* __restrict__ pair_part,
    const unsigned int* __restrict__ cnt_part, float* __restrict__ out)
{
    const int tid = threadIdx.x;
    float hub = 0.f, pr = 0.f;
    unsigned int cnt = 0;
    for (int k = tid; k < B_ROWS; k += 256) hub += hub_part[k];
    for (int k = tid; k < PAIR_BLOCKS; k += 256) {
        pr  += pair_part[k];
        cnt += cnt_part[k];
    }

    const int lane = tid & 63, wave = tid >> 6;
    #pragma unroll
    for (int off = 32; off > 0; off >>= 1) {
        hub += __shfl_down(hub, off, 64);
        pr  += __shfl_down(pr,  off, 64);
        cnt += __shfl_down(cnt, off, 64);
    }
    __shared__ float hw[4], pw[4];
    __shared__ unsigned int cw[4];
    if (lane == 0) { hw[wave] = hub; pw[wave] = pr; cw[wave] = cnt; }
    __syncthreads();
    if (tid == 0) {
        float H = hw[0] + hw[1] + hw[2] + hw[3];
        float P = pw[0] + pw[1] + pw[2] + pw[3];
        unsigned int C = cw[0] + cw[1] + cw[2] + cw[3];
        float n   = (float)C;
        float L_c = (n > 0.f) ? P / fmaxf(n, 1.f) : 0.f;
        float L_s = H / (float)(B_ROWS * 4);
        out[0] = L_c + L_s;
        out[1] = L_c;
        out[2] = L_s;
    }
}

extern "C" void kernel_launch(void* const* d_in, const int* in_sizes, int n_in,
                              void* d_out, int out_size, void* d_ws, size_t ws_size,
                              hipStream_t stream) {
    const float* z_ref  = (const float*)d_in[0];
    const float* z_perf = (const float*)d_in[1];
    const float* pred   = (const float*)d_in[2];
    const float* tgt    = (const float*)d_in[3];
    float* out = (float*)d_out;

    // Workspace layout (floats) — every slot written unconditionally each call:
    // [0,4096)=sim  [4096,8192)=overall  [8192,12288)=hub_part
    // [12288,13312)=pair_part  [13312,14336)=cnt_part (uint bits)
    float* ws        = (float*)d_ws;
    float* sim       = ws;
    float* overall   = ws + B_ROWS;
    float* hub_part  = ws + 2 * B_ROWS;
    float* pair_part = ws + 3 * B_ROWS;
    unsigned int* cnt_part = (unsigned int*)(ws + 3 * B_ROWS + PAIR_BLOCKS);

    sim_huber_kernel<<<B_ROWS, 256, 0, stream>>>(z_ref, z_perf, pred, tgt,
                                                 sim, overall, hub_part);
    pair_kernel<<<PAIR_BLOCKS, 256, 0, stream>>>(sim, overall, pair_part, cnt_part);
    finalize_kernel<<<1, 256, 0, stream>>>(hub_part, pair_part, cnt_part, out);
}